// Round 9
// baseline (554.367 us; speedup 1.0000x reference)
//
#include <hip/hip_runtime.h>

#define GAMMA 0.1f
#define MIN_R 0.1f
#define THR 256
#define NXCD 8

// ---------------- LJ force ---------------------------------------------------
__device__ __forceinline__ void lj_force(float dx, float dy, float dz,
                                         float& fx, float& fy, float& fz)
{
    float r2 = dx * dx + dy * dy + dz * dz;
    float rr = sqrtf(r2);
    float inv_norm = 1.0f / fmaxf(rr, 1e-12f);
    float rc = fmaxf(rr, MIN_R);
    float s1 = 1.0f / rc;                 // RC = 1
    float s2 = s1 * s1;
    float s6 = s2 * s2 * s2;
    float F = 4.0f * s6 * (12.0f * s6 - 6.0f) * s1;
    float sc = F * inv_norm;
    fx = sc * dx; fy = sc * dy; fz = sc * dz;
}

// ---------------- k0: zero the 8 replicas ------------------------------------
__global__ __launch_bounds__(THR) void zero_rep_kernel(float4* __restrict__ rep4,
                                                       int n4)
{
    const float4 z = make_float4(0.f, 0.f, 0.f, 0.f);
    for (int i = blockIdx.x * THR + threadIdx.x; i < n4; i += gridDim.x * THR)
        rep4[i] = z;
}

// ---------------- k1: per-edge force into XCD-private replica ----------------
__global__ __launch_bounds__(THR) void edge_atomic_xcd_kernel(
    const float* __restrict__ x, const int* __restrict__ src,
    const int* __restrict__ dst, float* __restrict__ rep,
    int n_edges, int n_out)
{
    // wave-uniform hardware XCD id -> replica whose lines only this XCD touches
    unsigned xcd;
    asm volatile("s_getreg_b32 %0, hwreg(HW_REG_XCC_ID)" : "=s"(xcd));
    float* __restrict__ myrep = rep + (size_t)(xcd & (NXCD - 1)) * (size_t)n_out;

    const int i4 = (blockIdx.x * THR + threadIdx.x) * 4;
    if (i4 + 3 < n_edges) {
        const int4 s4 = *(const int4*)(src + i4);
        const int4 d4 = *(const int4*)(dst + i4);
        const int sI[4] = {s4.x, s4.y, s4.z, s4.w};
        const int dI[4] = {d4.x, d4.y, d4.z, d4.w};
        float xs[4][3], xd[4][3];
        #pragma unroll
        for (int k = 0; k < 4; ++k) {
            const int s3 = 3 * sI[k], d3 = 3 * dI[k];
            xs[k][0] = x[s3 + 0]; xs[k][1] = x[s3 + 1]; xs[k][2] = x[s3 + 2];
            xd[k][0] = x[d3 + 0]; xd[k][1] = x[d3 + 1]; xd[k][2] = x[d3 + 2];
        }
        #pragma unroll
        for (int k = 0; k < 4; ++k) {
            float fx, fy, fz;
            lj_force(xd[k][0] - xs[k][0], xd[k][1] - xs[k][1],
                     xd[k][2] - xs[k][2], fx, fy, fz);
            const int d3 = 3 * dI[k];
            unsafeAtomicAdd(&myrep[d3 + 0], fx);
            unsafeAtomicAdd(&myrep[d3 + 1], fy);
            unsafeAtomicAdd(&myrep[d3 + 2], fz);
        }
    } else {
        for (int e = i4; e < n_edges; ++e) {
            const int s3 = 3 * src[e], d3 = 3 * dst[e];
            float fx, fy, fz;
            lj_force(x[d3 + 0] - x[s3 + 0], x[d3 + 1] - x[s3 + 1],
                     x[d3 + 2] - x[s3 + 2], fx, fy, fz);
            unsafeAtomicAdd(&myrep[d3 + 0], fx);
            unsafeAtomicAdd(&myrep[d3 + 1], fy);
            unsafeAtomicAdd(&myrep[d3 + 2], fz);
        }
    }
}

// ---------------- k2: merge replicas + fuse -gamma*v -------------------------
__global__ __launch_bounds__(THR) void merge_rep_kernel(
    const float* __restrict__ rep, const float* __restrict__ v,
    float* __restrict__ out, int n_out)
{
    int g = (blockIdx.x * THR + threadIdx.x) * 4;
    if (g + 3 < n_out) {
        float4 sum = make_float4(0.f, 0.f, 0.f, 0.f);
        #pragma unroll
        for (int k = 0; k < NXCD; ++k) {
            float4 p = *(const float4*)(rep + (size_t)k * n_out + g);
            sum.x += p.x; sum.y += p.y; sum.z += p.z; sum.w += p.w;
        }
        float4 vg = *(const float4*)(v + g);
        float4 o;
        o.x = sum.x - GAMMA * vg.x;
        o.y = sum.y - GAMMA * vg.y;
        o.z = sum.z - GAMMA * vg.z;
        o.w = sum.w - GAMMA * vg.w;
        *(float4*)(out + g) = o;
    } else {
        for (; g < n_out; ++g) {
            float sum = 0.0f;
            for (int k = 0; k < NXCD; ++k) sum += rep[(size_t)k * n_out + g];
            out[g] = sum - GAMMA * v[g];
        }
    }
}

// ---------------- fallback: direct atomics into out --------------------------
__global__ __launch_bounds__(THR) void init_out_kernel(
    const float* __restrict__ v, float* __restrict__ out, int n)
{
    int g = blockIdx.x * THR + threadIdx.x;
    if (g < n) out[g] = -GAMMA * v[g];
}

__global__ __launch_bounds__(THR) void edge_atomic_kernel(
    const float* __restrict__ x, const int* __restrict__ src,
    const int* __restrict__ dst, float* __restrict__ out, int n_edges)
{
    int e = blockIdx.x * THR + threadIdx.x;
    if (e < n_edges) {
        const int s3 = 3 * src[e], d3 = 3 * dst[e];
        float fx, fy, fz;
        lj_force(x[d3 + 0] - x[s3 + 0], x[d3 + 1] - x[s3 + 1],
                 x[d3 + 2] - x[s3 + 2], fx, fy, fz);
        unsafeAtomicAdd(&out[d3 + 0], fx);
        unsafeAtomicAdd(&out[d3 + 1], fy);
        unsafeAtomicAdd(&out[d3 + 2], fz);
    }
}

extern "C" void kernel_launch(void* const* d_in, const int* in_sizes, int n_in,
                              void* d_out, int out_size, void* d_ws, size_t ws_size,
                              hipStream_t stream) {
    const float* x   = (const float*)d_in[0];
    const float* v   = (const float*)d_in[1];
    const int*   src = (const int*)d_in[2];
    const int*   dst = (const int*)d_in[3];
    float* out = (float*)d_out;

    const int n_out = out_size;
    const int n_edges = in_sizes[2];

    const size_t rep_bytes = (size_t)NXCD * n_out * sizeof(float);

    const int ge = ((n_edges + 3) / 4 + THR - 1) / THR;

    if (rep_bytes <= ws_size) {
        float* rep = (float*)d_ws;
        const int n4 = (int)((rep_bytes / sizeof(float)) / 4);
        zero_rep_kernel<<<2048, THR, 0, stream>>>((float4*)rep, n4);
        edge_atomic_xcd_kernel<<<ge, THR, 0, stream>>>(x, src, dst, rep,
                                                       n_edges, n_out);
        const int gm = ((n_out + 3) / 4 + THR - 1) / THR;
        merge_rep_kernel<<<gm, THR, 0, stream>>>(rep, v, out, n_out);
    } else {
        init_out_kernel<<<(n_out + THR - 1) / THR, THR, 0, stream>>>(v, out, n_out);
        edge_atomic_kernel<<<(n_edges + THR - 1) / THR, THR, 0, stream>>>(
            x, src, dst, out, n_edges);
    }
}

// Round 11
// 158.927 us; speedup vs baseline: 3.4882x; 3.4882x over previous
//
#include <hip/hip_runtime.h>

#define GAMMA 0.1f
#define MIN_R 0.1f

// Counting-sort parameters
#define NR 512                  // nodes per bin (power of 2)
#define LOG_NR 9
#define NB 1024                 // blocks for count/scatter kernels
#define THR_AC 256              // threads for count/scatter
#define RMAX 256                // max bins (n_nodes <= 131072)

// scatter LDS-staging batch
#define SC_BS 4096              // edges per batch (payload 16 KB)
#define SC_EPT (SC_BS / THR_AC) // 16 edges per thread per batch

typedef unsigned int u32;

// ---------------- LJ force ---------------------------------------------------
__device__ __forceinline__ void lj_accum(float4 xd, float4 xs,
                                         float& ax, float& ay, float& az)
{
    float dx = xd.x - xs.x, dy = xd.y - xs.y, dz = xd.z - xs.z;
    float r2 = dx * dx + dy * dy + dz * dz;
    float rr = sqrtf(r2);
    float inv_norm = 1.0f / fmaxf(rr, 1e-12f);
    float rc = fmaxf(rr, MIN_R);
    float s1 = 1.0f / rc;                 // RC = 1
    float s2 = s1 * s1;
    float s6 = s2 * s2 * s2;
    float F = 4.0f * s6 * (12.0f * s6 - 6.0f) * s1;
    float sc = F * inv_norm;
    ax += sc * dx; ay += sc * dy; az += sc * dz;
}

// ---------------- k0: pack x into padded float4 ------------------------------
__global__ void prep_xp_kernel(const float* __restrict__ x,
                               float4* __restrict__ xp, int n_nodes)
{
    int i = blockIdx.x * blockDim.x + threadIdx.x;
    if (i < n_nodes)
        xp[i] = make_float4(x[3 * i + 0], x[3 * i + 1], x[3 * i + 2], 0.0f);
}

// ---------------- k1: per-block bin histogram --------------------------------
__global__ __launch_bounds__(THR_AC) void count_kernel(
    const int* __restrict__ dst, u32* __restrict__ counts,
    int n_edges, int epb, int R)
{
    __shared__ u32 hist[RMAX];
    const int b = blockIdx.x, t = threadIdx.x;
    if (t < RMAX) hist[t] = 0;
    __syncthreads();
    const int s0 = b * epb;
    const int s1 = min(s0 + epb, n_edges);
    for (int base = s0 + t * 4; base < s1; base += THR_AC * 4) {
        if (base + 3 < s1) {
            int4 d4 = *(const int4*)(dst + base);
            atomicAdd(&hist[(u32)d4.x >> LOG_NR], 1u);
            atomicAdd(&hist[(u32)d4.y >> LOG_NR], 1u);
            atomicAdd(&hist[(u32)d4.z >> LOG_NR], 1u);
            atomicAdd(&hist[(u32)d4.w >> LOG_NR], 1u);
        } else {
            for (int e = base; e < s1; ++e)
                atomicAdd(&hist[(u32)dst[e] >> LOG_NR], 1u);
        }
    }
    __syncthreads();
    if (t < R) counts[b * R + t] = hist[t];
}

// ---------------- k2: per-bin exclusive scan over blocks ---------------------
__global__ __launch_bounds__(NB) void scan_blocks_kernel(
    const u32* __restrict__ counts, u32* __restrict__ bases,
    u32* __restrict__ totals, int R)
{
    __shared__ u32 s[NB];
    const int r = blockIdx.x, t = threadIdx.x;
    u32 orig = counts[t * R + r];
    s[t] = orig;
    __syncthreads();
    for (int d = 1; d < NB; d <<= 1) {
        u32 v = (t >= d) ? s[t - d] : 0u;
        __syncthreads();
        s[t] += v;
        __syncthreads();
    }
    bases[t * R + r] = s[t] - orig;           // exclusive
    if (t == NB - 1) totals[r] = s[t];
}

// ---------------- k3: exclusive scan over bins -------------------------------
__global__ void scan_bins_kernel(const u32* __restrict__ totals,
                                 u32* __restrict__ offsets,
                                 u32* __restrict__ starts,
                                 int R, int n_nodes)
{
    __shared__ u32 tot[RMAX];
    const int t = threadIdx.x;
    if (t < R) tot[t] = totals[t];
    __syncthreads();
    if (t == 0) {
        u32 off = 0;
        for (int r = 0; r < R; ++r) { offsets[r] = off; off += tot[r]; }
        offsets[R] = off;
        starts[n_nodes] = off;                // grand total == n_edges
    }
}

// ---------------- k4: LDS-staged scatter into bin-contiguous pk1 -------------
__global__ __launch_bounds__(THR_AC) void scatter_kernel(
    const int* __restrict__ src, const int* __restrict__ dst,
    const u32* __restrict__ bases, const u32* __restrict__ offsets,
    u32* __restrict__ pk1, int n_edges, int epb, int R)
{
    __shared__ u32 payload[SC_BS];            // 16 KB
    __shared__ unsigned char binof[SC_BS];    // 4 KB
    __shared__ u32 hist[RMAX], loff[RMAX], lcur[RMAX], gcur[RMAX];
    const int b = blockIdx.x, t = threadIdx.x;
    if (t < RMAX) {
        u32 g = 0;
        if (t < R) g = offsets[t] + bases[b * R + t];
        gcur[t] = g;
    }
    const int s0 = b * epb;
    const int s1 = min(s0 + epb, n_edges);

    for (int bs = s0; bs < s1; bs += SC_BS) {
        const int n = min(SC_BS, s1 - bs);
        const int lim = bs + n;
        if (t < RMAX) hist[t] = 0;
        __syncthreads();

        // pass 1: per-batch histogram
        {
            const int base = bs + t * SC_EPT;
            #pragma unroll
            for (int k = 0; k < SC_EPT; k += 4) {
                int e = base + k;
                if (e + 3 < lim) {
                    int4 d4 = *(const int4*)(dst + e);
                    atomicAdd(&hist[(u32)d4.x >> LOG_NR], 1u);
                    atomicAdd(&hist[(u32)d4.y >> LOG_NR], 1u);
                    atomicAdd(&hist[(u32)d4.z >> LOG_NR], 1u);
                    atomicAdd(&hist[(u32)d4.w >> LOG_NR], 1u);
                } else {
                    for (int q = e; q < lim; ++q)
                        atomicAdd(&hist[(u32)dst[q] >> LOG_NR], 1u);
                    break;
                }
            }
        }
        __syncthreads();

        // exclusive scan over RMAX bins (Hillis-Steele)
        if (t < RMAX) loff[t] = hist[t];
        __syncthreads();
        for (int d = 1; d < RMAX; d <<= 1) {
            u32 a = 0;
            if (t < RMAX && t >= d) a = loff[t - d];
            __syncthreads();
            if (t < RMAX) loff[t] += a;
            __syncthreads();
        }
        {
            u32 ex = 0;
            if (t < RMAX) ex = loff[t] - hist[t];
            __syncthreads();
            if (t < RMAX) { loff[t] = ex; lcur[t] = ex; }
        }
        __syncthreads();

        // pass 2: deposit into LDS (sorted by bin)
        {
            const int base = bs + t * SC_EPT;
            #pragma unroll
            for (int k = 0; k < SC_EPT; k += 4) {
                int e = base + k;
                if (e + 3 < lim) {
                    int4 d4 = *(const int4*)(dst + e);
                    int4 s4 = *(const int4*)(src + e);
                    #pragma unroll
                    for (int q = 0; q < 4; ++q) {
                        u32 d = (u32)((q == 0) ? d4.x : (q == 1) ? d4.y : (q == 2) ? d4.z : d4.w);
                        u32 sv = (u32)((q == 0) ? s4.x : (q == 1) ? s4.y : (q == 2) ? s4.z : s4.w);
                        u32 r = d >> LOG_NR;
                        u32 w = ((d & (NR - 1)) << 17) | sv;
                        u32 slot = atomicAdd(&lcur[r], 1u);
                        payload[slot] = w;
                        binof[slot] = (unsigned char)r;
                    }
                } else {
                    for (int q = e; q < lim; ++q) {
                        u32 d = (u32)dst[q];
                        u32 sv = (u32)src[q];
                        u32 r = d >> LOG_NR;
                        u32 w = ((d & (NR - 1)) << 17) | sv;
                        u32 slot = atomicAdd(&lcur[r], 1u);
                        payload[slot] = w;
                        binof[slot] = (unsigned char)r;
                    }
                    break;
                }
            }
        }
        __syncthreads();

        // flush: consecutive LDS slots -> consecutive global positions
        for (int j = t; j < n; j += THR_AC) {
            u32 w = payload[j];
            u32 r = binof[j];
            pk1[gcur[r] + ((u32)j - loff[r])] = w;
        }
        __syncthreads();
        if (t < RMAX) gcur[t] += hist[t];
    }
}

// ---------------- k5: per-bin counting sort by node (exclusive window) -------
__global__ __launch_bounds__(256) void binsort_kernel(
    const u32* __restrict__ pk1, const u32* __restrict__ offsets,
    u32* __restrict__ starts, u32* __restrict__ pk2, int n_nodes)
{
    __shared__ u32 hist[NR], cur[NR];
    const int b = blockIdx.x, t = threadIdx.x;
    const int e0 = (int)offsets[b];
    const int e1 = (int)offsets[b + 1];
    hist[t] = 0u; hist[t + 256] = 0u;
    __syncthreads();

    // pass 1: histogram over in-bin node ids (4-deep MLP)
    {
        int e = e0 + t;
        for (; e + 768 < e1; e += 1024) {
            u32 a = pk1[e], b2 = pk1[e + 256], c = pk1[e + 512], d = pk1[e + 768];
            atomicAdd(&hist[a >> 17], 1u);
            atomicAdd(&hist[b2 >> 17], 1u);
            atomicAdd(&hist[c >> 17], 1u);
            atomicAdd(&hist[d >> 17], 1u);
        }
        for (; e < e1; e += 256)
            atomicAdd(&hist[pk1[e] >> 17], 1u);
    }
    __syncthreads();

    // inclusive scan over 512 entries, 2 per thread
    u32 h0 = hist[t], h1 = hist[t + 256];
    cur[t] = h0; cur[t + 256] = h1;
    __syncthreads();
    for (int d = 1; d < NR; d <<= 1) {
        u32 a0 = (t >= d) ? cur[t - d] : 0u;
        u32 a1 = cur[t + 256 - d];            // t+256 >= d always (d <= 256)
        __syncthreads();
        cur[t] += a0; cur[t + 256] += a1;
        __syncthreads();
    }
    u32 x0 = cur[t] - h0, x1 = cur[t + 256] - h1;
    const int n0 = (b << LOG_NR) + t, n1 = n0 + 256;
    if (n0 < n_nodes) starts[n0] = (u32)e0 + x0;
    if (n1 < n_nodes) starts[n1] = (u32)e0 + x1;
    __syncthreads();
    cur[t] = x0; cur[t + 256] = x1;
    __syncthreads();

    // pass 2: scatter within the block-exclusive window [e0, e1)
    {
        int e = e0 + t;
        for (; e + 768 < e1; e += 1024) {
            u32 wa = pk1[e], wb = pk1[e + 256], wc = pk1[e + 512], wd = pk1[e + 768];
            u32 pa = atomicAdd(&cur[wa >> 17], 1u);
            u32 pb = atomicAdd(&cur[wb >> 17], 1u);
            u32 pc = atomicAdd(&cur[wc >> 17], 1u);
            u32 pd = atomicAdd(&cur[wd >> 17], 1u);
            pk2[(u32)e0 + pa] = wa & 0x1FFFFu;
            pk2[(u32)e0 + pb] = wb & 0x1FFFFu;
            pk2[(u32)e0 + pc] = wc & 0x1FFFFu;
            pk2[(u32)e0 + pd] = wd & 0x1FFFFu;
        }
        for (; e < e1; e += 256) {
            u32 w = pk1[e];
            u32 pos = atomicAdd(&cur[w >> 17], 1u);
            pk2[(u32)e0 + pos] = w & 0x1FFFFu;
        }
    }
}

// ---------------- k6: per-node register gather (2 thr/node) + fused out ------
__global__ __launch_bounds__(256) void process_kernel(
    const float4* __restrict__ xp, const u32* __restrict__ pk2,
    const u32* __restrict__ starts, const float* __restrict__ v,
    float* __restrict__ out, int n_nodes)
{
    const int gid = blockIdx.x * 256 + threadIdx.x;
    const int d = gid >> 1;
    const int half = gid & 1;
    if (d >= n_nodes) return;
    const float4 xd = xp[d];
    const int e1 = (int)starts[d + 1];
    int e = (int)starts[d] + half;
    float ax = 0.f, ay = 0.f, az = 0.f;

    for (; e + 6 < e1; e += 8) {
        u32 sA = pk2[e], sB = pk2[e + 2], sC = pk2[e + 4], sD = pk2[e + 6];
        float4 a = xp[sA];
        float4 b = xp[sB];
        float4 c = xp[sC];
        float4 f = xp[sD];
        lj_accum(xd, a, ax, ay, az);
        lj_accum(xd, b, ax, ay, az);
        lj_accum(xd, c, ax, ay, az);
        lj_accum(xd, f, ax, ay, az);
    }
    for (; e < e1; e += 2) {
        float4 a = xp[pk2[e]];
        lj_accum(xd, a, ax, ay, az);
    }

    ax += __shfl_xor(ax, 1);
    ay += __shfl_xor(ay, 1);
    az += __shfl_xor(az, 1);
    if (half == 0) {
        out[3 * d + 0] = ax - GAMMA * v[3 * d + 0];
        out[3 * d + 1] = ay - GAMMA * v[3 * d + 1];
        out[3 * d + 2] = az - GAMMA * v[3 * d + 2];
    }
}

// ---------------- fallback path ----------------------------------------------
__global__ void init_out_kernel(const float* __restrict__ v,
                                float* __restrict__ out, int n) {
    int i = blockIdx.x * blockDim.x + threadIdx.x;
    if (i < n) out[i] = -GAMMA * v[i];
}

__global__ void edge_atomic_kernel(const float* __restrict__ x,
                                   const int* __restrict__ src,
                                   const int* __restrict__ dst,
                                   float* __restrict__ out, int n_edges) {
    int e = blockIdx.x * blockDim.x + threadIdx.x;
    if (e < n_edges) {
        const int s3 = 3 * src[e], d3 = 3 * dst[e];
        float dx = x[d3 + 0] - x[s3 + 0];
        float dy = x[d3 + 1] - x[s3 + 1];
        float dz = x[d3 + 2] - x[s3 + 2];
        float r2 = dx * dx + dy * dy + dz * dz;
        float rr = sqrtf(r2);
        float inv_norm = 1.0f / fmaxf(rr, 1e-12f);
        float rc = fmaxf(rr, MIN_R);
        float s1 = 1.0f / rc;
        float s2 = s1 * s1;
        float s6 = s2 * s2 * s2;
        float F = 4.0f * s6 * (12.0f * s6 - 6.0f) * s1;
        float sc = F * inv_norm;
        unsafeAtomicAdd(&out[d3 + 0], sc * dx);
        unsafeAtomicAdd(&out[d3 + 1], sc * dy);
        unsafeAtomicAdd(&out[d3 + 2], sc * dz);
    }
}

extern "C" void kernel_launch(void* const* d_in, const int* in_sizes, int n_in,
                              void* d_out, int out_size, void* d_ws, size_t ws_size,
                              hipStream_t stream) {
    const float* x   = (const float*)d_in[0];
    const float* v   = (const float*)d_in[1];
    const int*   src = (const int*)d_in[2];
    const int*   dst = (const int*)d_in[3];
    float* out = (float*)d_out;

    const int n_out   = out_size;
    const int n_nodes = out_size / 3;
    const int n_edges = in_sizes[2];
    const int R = (n_nodes + NR - 1) / NR;

    // ---- ws layout (bytes) ----
    size_t off = 0;
    auto take = [&off](size_t bytes) {
        size_t o = off;
        off = (off + bytes + 63) & ~(size_t)63;
        return o;
    };
    const size_t xp_o      = take((size_t)n_nodes * 16);
    const size_t counts_o  = take((size_t)NB * R * 4);
    const size_t bases_o   = take((size_t)NB * R * 4);
    const size_t totals_o  = take((size_t)R * 4);
    const size_t offsets_o = take((size_t)(R + 1) * 4);
    const size_t starts_o  = take((size_t)(n_nodes + 1) * 4);
    const size_t pk1_o     = take((size_t)n_edges * 4);
    const size_t pk2_o     = take((size_t)n_edges * 4);
    const size_t need = off;

    const int blk = 256;
    if (n_nodes <= (1 << 17) && R <= RMAX && need <= ws_size) {
        float4* xp   = (float4*)((char*)d_ws + xp_o);
        u32* counts  = (u32*)((char*)d_ws + counts_o);
        u32* bases   = (u32*)((char*)d_ws + bases_o);
        u32* totals  = (u32*)((char*)d_ws + totals_o);
        u32* offsets = (u32*)((char*)d_ws + offsets_o);
        u32* starts  = (u32*)((char*)d_ws + starts_o);
        u32* pk1     = (u32*)((char*)d_ws + pk1_o);
        u32* pk2     = (u32*)((char*)d_ws + pk2_o);

        int epb = ((n_edges + NB - 1) / NB + 3) & ~3;

        prep_xp_kernel<<<(n_nodes + blk - 1) / blk, blk, 0, stream>>>(x, xp, n_nodes);
        count_kernel<<<NB, THR_AC, 0, stream>>>(dst, counts, n_edges, epb, R);
        scan_blocks_kernel<<<R, NB, 0, stream>>>(counts, bases, totals, R);
        scan_bins_kernel<<<1, RMAX, 0, stream>>>(totals, offsets, starts, R, n_nodes);
        scatter_kernel<<<NB, THR_AC, 0, stream>>>(src, dst, bases, offsets, pk1,
                                                  n_edges, epb, R);
        binsort_kernel<<<R, 256, 0, stream>>>(pk1, offsets, starts, pk2, n_nodes);
        process_kernel<<<(2 * n_nodes + blk - 1) / blk, blk, 0, stream>>>(
            xp, pk2, starts, v, out, n_nodes);
    } else {
        init_out_kernel<<<(n_out + blk - 1) / blk, blk, 0, stream>>>(v, out, n_out);
        edge_atomic_kernel<<<(n_edges + blk - 1) / blk, blk, 0, stream>>>(
            x, src, dst, out, n_edges);
    }
}

// Round 12
// 149.983 us; speedup vs baseline: 3.6962x; 1.0596x over previous
//
#include <hip/hip_runtime.h>

#define GAMMA 0.1f
#define MIN_R 0.1f

#define NR 512                  // nodes per bin (power of 2)
#define LOG_NR 9
#define RMAX 256                // max bins (n_nodes <= 131072)
#define SC_BS 4096              // edges per scatter block (private chunk)
#define THR 256
#define THR_B 512               // binsort block size

typedef unsigned int u32;

// ---------------- 64-lane inclusive scan via shfl ----------------------------
__device__ __forceinline__ u32 wave_incl_scan(u32 x) {
    #pragma unroll
    for (int d = 1; d < 64; d <<= 1) {
        u32 y = __shfl_up(x, d);
        if ((int)(threadIdx.x & 63) >= d) x += y;
    }
    return x;
}

// ---------------- LJ force accumulate ----------------------------------------
__device__ __forceinline__ void lj_accum(float4 xd, float4 xs,
                                         float& ax, float& ay, float& az)
{
    float dx = xd.x - xs.x, dy = xd.y - xs.y, dz = xd.z - xs.z;
    float r2 = dx * dx + dy * dy + dz * dz;
    float rr = sqrtf(r2);
    float inv_norm = 1.0f / fmaxf(rr, 1e-12f);
    float rc = fmaxf(rr, MIN_R);
    float s1 = 1.0f / rc;                 // RC = 1
    float s2 = s1 * s1;
    float s6 = s2 * s2 * s2;
    float F = 4.0f * s6 * (12.0f * s6 - 6.0f) * s1;
    float sc = F * inv_norm;
    ax += sc * dx; ay += sc * dy; az += sc * dz;
}

// ---------------- k1: block-private bin-sorted scatter (+ xp pack) -----------
// Block b sorts its SC_BS-edge batch by bin in LDS, writes it to its private
// chunk pk1[b*SC_BS ..] (coalesced), and records tab[b][r] = (boff<<13)|cnt.
__global__ __launch_bounds__(THR) void scatter_kernel(
    const float* __restrict__ x, const int* __restrict__ src,
    const int* __restrict__ dst, float4* __restrict__ xp,
    u32* __restrict__ pk1, u32* __restrict__ tab,
    int n_nodes, int n_edges, int NBv, int R)
{
    __shared__ u32 payload[SC_BS];        // 16 KB
    __shared__ u32 hist[RMAX], loff[RMAX], lcur[RMAX];
    __shared__ u32 wsum[4];
    const int b = blockIdx.x, t = threadIdx.x;

    // folded prep: pack x -> xp (grid-stride)
    for (int i = b * THR + t; i < n_nodes; i += NBv * THR)
        xp[i] = make_float4(x[3 * i + 0], x[3 * i + 1], x[3 * i + 2], 0.0f);

    const int s0 = b * SC_BS;
    const int n  = min(SC_BS, n_edges - s0);
    const int lim = s0 + n;

    hist[t] = 0u;
    __syncthreads();

    // pass 1: batch histogram over bins
    for (int e = s0 + t * 4; e < lim; e += THR * 4) {
        if (e + 3 < lim) {
            int4 d4 = *(const int4*)(dst + e);
            atomicAdd(&hist[(u32)d4.x >> LOG_NR], 1u);
            atomicAdd(&hist[(u32)d4.y >> LOG_NR], 1u);
            atomicAdd(&hist[(u32)d4.z >> LOG_NR], 1u);
            atomicAdd(&hist[(u32)d4.w >> LOG_NR], 1u);
        } else {
            for (int q = e; q < lim; ++q)
                atomicAdd(&hist[(u32)dst[q] >> LOG_NR], 1u);
        }
    }
    __syncthreads();

    // exclusive scan over 256 bins (shfl + 1 barrier)
    {
        u32 h = hist[t];
        u32 inc = wave_incl_scan(h);
        if ((t & 63) == 63) wsum[t >> 6] = inc;
        __syncthreads();
        u32 pre = 0;
        #pragma unroll
        for (int w = 0; w < 4; ++w) if (w < (t >> 6)) pre += wsum[w];
        u32 ex = pre + inc - h;
        loff[t] = ex; lcur[t] = ex;
    }
    __syncthreads();

    // pass 2: deposit bin-sorted into LDS
    for (int e = s0 + t * 4; e < lim; e += THR * 4) {
        if (e + 3 < lim) {
            int4 d4 = *(const int4*)(dst + e);
            int4 s4 = *(const int4*)(src + e);
            #pragma unroll
            for (int q = 0; q < 4; ++q) {
                u32 d = (u32)((q == 0) ? d4.x : (q == 1) ? d4.y : (q == 2) ? d4.z : d4.w);
                u32 sv = (u32)((q == 0) ? s4.x : (q == 1) ? s4.y : (q == 2) ? s4.z : s4.w);
                u32 r = d >> LOG_NR;
                u32 w = ((d & (NR - 1)) << 17) | sv;
                u32 slot = atomicAdd(&lcur[r], 1u);
                payload[slot] = w;
            }
        } else {
            for (int q = e; q < lim; ++q) {
                u32 d = (u32)dst[q];
                u32 sv = (u32)src[q];
                u32 r = d >> LOG_NR;
                u32 w = ((d & (NR - 1)) << 17) | sv;
                u32 slot = atomicAdd(&lcur[r], 1u);
                payload[slot] = w;
            }
        }
    }
    __syncthreads();

    // flush chunk (coalesced, block-private) + table row
    for (int j = t; j < n; j += THR) pk1[s0 + j] = payload[j];
    if (t < R) tab[(size_t)b * R + t] = (loff[t] << 13) | hist[t];
}

// ---------------- k2: per-bin totals from tab --------------------------------
__global__ __launch_bounds__(THR) void rowsum_kernel(
    const u32* __restrict__ tab, u32* __restrict__ btot, int NBv, int R)
{
    __shared__ u32 red[THR];
    const int r = blockIdx.x, t = threadIdx.x;
    u32 s = 0;
    for (int j = t; j < NBv; j += THR) s += tab[(size_t)j * R + r] & 8191u;
    red[t] = s;
    __syncthreads();
    for (int d = THR / 2; d > 0; d >>= 1) {
        if (t < d) red[t] += red[t + d];
        __syncthreads();
    }
    if (t == 0) btot[r] = red[0];
}

// ---------------- k3: exclusive scan over bins (1 block) ---------------------
__global__ __launch_bounds__(THR) void binscan_kernel(
    const u32* __restrict__ btot, u32* __restrict__ offsets,
    u32* __restrict__ starts, int R, int n_nodes)
{
    __shared__ u32 wsum[4];
    const int t = threadIdx.x;
    u32 v = (t < R) ? btot[t] : 0u;
    u32 inc = wave_incl_scan(v);
    if ((t & 63) == 63) wsum[t >> 6] = inc;
    __syncthreads();
    u32 pre = 0;
    #pragma unroll
    for (int w = 0; w < 4; ++w) if (w < (t >> 6)) pre += wsum[w];
    u32 ti = pre + inc;
    if (t < R) offsets[t] = ti - v;
    if (t == THR - 1) { offsets[R] = ti; starts[n_nodes] = ti; }
}

// ---------------- k4: per-bin sort-to-node (ragged gather, excl window) ------
__global__ __launch_bounds__(THR_B) void binsort_kernel(
    const u32* __restrict__ pk1, const u32* __restrict__ tab,
    const u32* __restrict__ offsets, u32* __restrict__ starts,
    u32* __restrict__ pk2, int n_nodes, int NBv, int R)
{
    __shared__ u32 hist[NR], cur[NR];
    __shared__ u32 wsum[8];
    const int r = blockIdx.x, t = threadIdx.x;
    hist[t] = 0u;
    __syncthreads();

    // pass A: in-bin node histogram over ragged segments
    for (int j = t; j < NBv; j += THR_B) {
        u32 w = tab[(size_t)j * R + r];
        int cnt = (int)(w & 8191u);
        const u32* seg = pk1 + (size_t)j * SC_BS + (w >> 13);
        int k = 0;
        for (; k + 3 < cnt; k += 4) {
            u32 a = seg[k], b2 = seg[k + 1], c = seg[k + 2], d = seg[k + 3];
            atomicAdd(&hist[a >> 17], 1u);
            atomicAdd(&hist[b2 >> 17], 1u);
            atomicAdd(&hist[c >> 17], 1u);
            atomicAdd(&hist[d >> 17], 1u);
        }
        for (; k < cnt; ++k) atomicAdd(&hist[seg[k] >> 17], 1u);
    }
    __syncthreads();

    // exclusive scan over 512 (shfl, 8 waves)
    u32 h = hist[t];
    u32 inc = wave_incl_scan(h);
    if ((t & 63) == 63) wsum[t >> 6] = inc;
    __syncthreads();
    u32 pre = 0;
    #pragma unroll
    for (int w = 0; w < 8; ++w) if (w < (t >> 6)) pre += wsum[w];
    u32 ex = pre + inc - h;
    const u32 e0 = offsets[r];
    const int node = (r << LOG_NR) + t;
    if (node < n_nodes) starts[node] = e0 + ex;
    cur[t] = ex;
    __syncthreads();

    // pass B: place into pk2 within the block-exclusive window
    for (int j = t; j < NBv; j += THR_B) {
        u32 w = tab[(size_t)j * R + r];
        int cnt = (int)(w & 8191u);
        const u32* seg = pk1 + (size_t)j * SC_BS + (w >> 13);
        int k = 0;
        for (; k + 3 < cnt; k += 4) {
            u32 w0 = seg[k], w1 = seg[k + 1], w2 = seg[k + 2], w3 = seg[k + 3];
            u32 p0 = atomicAdd(&cur[w0 >> 17], 1u);
            u32 p1 = atomicAdd(&cur[w1 >> 17], 1u);
            u32 p2 = atomicAdd(&cur[w2 >> 17], 1u);
            u32 p3 = atomicAdd(&cur[w3 >> 17], 1u);
            pk2[e0 + p0] = w0 & 0x1FFFFu;
            pk2[e0 + p1] = w1 & 0x1FFFFu;
            pk2[e0 + p2] = w2 & 0x1FFFFu;
            pk2[e0 + p3] = w3 & 0x1FFFFu;
        }
        for (; k < cnt; ++k) {
            u32 w0 = seg[k];
            u32 p0 = atomicAdd(&cur[w0 >> 17], 1u);
            pk2[e0 + p0] = w0 & 0x1FFFFu;
        }
    }
}

// ---------------- k5: per-node register gather (2 thr/node) + fused out ------
__global__ __launch_bounds__(THR) void process_kernel(
    const float4* __restrict__ xp, const u32* __restrict__ pk2,
    const u32* __restrict__ starts, const float* __restrict__ v,
    float* __restrict__ out, int n_nodes)
{
    const int gid = blockIdx.x * THR + threadIdx.x;
    const int d = gid >> 1;
    const int half = gid & 1;
    if (d >= n_nodes) return;
    const float4 xd = xp[d];
    const int e1 = (int)starts[d + 1];
    int e = (int)starts[d] + half;
    float ax = 0.f, ay = 0.f, az = 0.f;

    for (; e + 14 < e1; e += 16) {
        u32 i0 = pk2[e],      i1 = pk2[e + 2],  i2 = pk2[e + 4],  i3 = pk2[e + 6];
        u32 i4 = pk2[e + 8],  i5 = pk2[e + 10], i6 = pk2[e + 12], i7 = pk2[e + 14];
        float4 a0 = xp[i0], a1 = xp[i1], a2 = xp[i2], a3 = xp[i3];
        float4 a4 = xp[i4], a5 = xp[i5], a6 = xp[i6], a7 = xp[i7];
        lj_accum(xd, a0, ax, ay, az);
        lj_accum(xd, a1, ax, ay, az);
        lj_accum(xd, a2, ax, ay, az);
        lj_accum(xd, a3, ax, ay, az);
        lj_accum(xd, a4, ax, ay, az);
        lj_accum(xd, a5, ax, ay, az);
        lj_accum(xd, a6, ax, ay, az);
        lj_accum(xd, a7, ax, ay, az);
    }
    for (; e + 6 < e1; e += 8) {
        u32 i0 = pk2[e], i1 = pk2[e + 2], i2 = pk2[e + 4], i3 = pk2[e + 6];
        float4 a0 = xp[i0], a1 = xp[i1], a2 = xp[i2], a3 = xp[i3];
        lj_accum(xd, a0, ax, ay, az);
        lj_accum(xd, a1, ax, ay, az);
        lj_accum(xd, a2, ax, ay, az);
        lj_accum(xd, a3, ax, ay, az);
    }
    for (; e < e1; e += 2) {
        float4 a = xp[pk2[e]];
        lj_accum(xd, a, ax, ay, az);
    }

    ax += __shfl_xor(ax, 1);
    ay += __shfl_xor(ay, 1);
    az += __shfl_xor(az, 1);
    if (half == 0) {
        out[3 * d + 0] = ax - GAMMA * v[3 * d + 0];
        out[3 * d + 1] = ay - GAMMA * v[3 * d + 1];
        out[3 * d + 2] = az - GAMMA * v[3 * d + 2];
    }
}

// ---------------- fallback path ----------------------------------------------
__global__ void init_out_kernel(const float* __restrict__ v,
                                float* __restrict__ out, int n) {
    int i = blockIdx.x * blockDim.x + threadIdx.x;
    if (i < n) out[i] = -GAMMA * v[i];
}

__global__ void edge_atomic_kernel(const float* __restrict__ x,
                                   const int* __restrict__ src,
                                   const int* __restrict__ dst,
                                   float* __restrict__ out, int n_edges) {
    int e = blockIdx.x * blockDim.x + threadIdx.x;
    if (e < n_edges) {
        const int s3 = 3 * src[e], d3 = 3 * dst[e];
        float dx = x[d3 + 0] - x[s3 + 0];
        float dy = x[d3 + 1] - x[s3 + 1];
        float dz = x[d3 + 2] - x[s3 + 2];
        float r2 = dx * dx + dy * dy + dz * dz;
        float rr = sqrtf(r2);
        float inv_norm = 1.0f / fmaxf(rr, 1e-12f);
        float rc = fmaxf(rr, MIN_R);
        float s1 = 1.0f / rc;
        float s2 = s1 * s1;
        float s6 = s2 * s2 * s2;
        float F = 4.0f * s6 * (12.0f * s6 - 6.0f) * s1;
        float sc = F * inv_norm;
        unsafeAtomicAdd(&out[d3 + 0], sc * dx);
        unsafeAtomicAdd(&out[d3 + 1], sc * dy);
        unsafeAtomicAdd(&out[d3 + 2], sc * dz);
    }
}

extern "C" void kernel_launch(void* const* d_in, const int* in_sizes, int n_in,
                              void* d_out, int out_size, void* d_ws, size_t ws_size,
                              hipStream_t stream) {
    const float* x   = (const float*)d_in[0];
    const float* v   = (const float*)d_in[1];
    const int*   src = (const int*)d_in[2];
    const int*   dst = (const int*)d_in[3];
    float* out = (float*)d_out;

    const int n_out   = out_size;
    const int n_nodes = out_size / 3;
    const int n_edges = in_sizes[2];
    const int R   = (n_nodes + NR - 1) / NR;
    const int NBv = (n_edges + SC_BS - 1) / SC_BS;

    // ---- ws layout (bytes) ----
    size_t off = 0;
    auto take = [&off](size_t bytes) {
        size_t o = off;
        off = (off + bytes + 63) & ~(size_t)63;
        return o;
    };
    const size_t xp_o      = take((size_t)n_nodes * 16);
    const size_t tab_o     = take((size_t)NBv * R * 4);
    const size_t btot_o    = take((size_t)R * 4);
    const size_t offsets_o = take((size_t)(R + 1) * 4);
    const size_t starts_o  = take((size_t)(n_nodes + 1) * 4);
    const size_t pk1_o     = take((size_t)NBv * SC_BS * 4);
    const size_t pk2_o     = take((size_t)n_edges * 4);
    const size_t need = off;

    if (n_nodes <= (1 << 17) && R <= RMAX && need <= ws_size) {
        float4* xp   = (float4*)((char*)d_ws + xp_o);
        u32* tab     = (u32*)((char*)d_ws + tab_o);
        u32* btot    = (u32*)((char*)d_ws + btot_o);
        u32* offsets = (u32*)((char*)d_ws + offsets_o);
        u32* starts  = (u32*)((char*)d_ws + starts_o);
        u32* pk1     = (u32*)((char*)d_ws + pk1_o);
        u32* pk2     = (u32*)((char*)d_ws + pk2_o);

        scatter_kernel<<<NBv, THR, 0, stream>>>(x, src, dst, xp, pk1, tab,
                                                n_nodes, n_edges, NBv, R);
        rowsum_kernel<<<R, THR, 0, stream>>>(tab, btot, NBv, R);
        binscan_kernel<<<1, THR, 0, stream>>>(btot, offsets, starts, R, n_nodes);
        binsort_kernel<<<R, THR_B, 0, stream>>>(pk1, tab, offsets, starts, pk2,
                                                n_nodes, NBv, R);
        process_kernel<<<(2 * n_nodes + THR - 1) / THR, THR, 0, stream>>>(
            xp, pk2, starts, v, out, n_nodes);
    } else {
        init_out_kernel<<<(n_out + THR - 1) / THR, THR, 0, stream>>>(v, out, n_out);
        edge_atomic_kernel<<<(n_edges + THR - 1) / THR, THR, 0, stream>>>(
            x, src, dst, out, n_edges);
    }
}

// Round 13
// 115.286 us; speedup vs baseline: 4.8086x; 1.3010x over previous
//
#include <hip/hip_runtime.h>

#define GAMMA 0.1f
#define MIN_R 0.1f

#define NR 256                  // nodes per bin
#define LOG_NR 8
#define RMAXB 512               // max bins (n_nodes <= 131072)
#define SC_BS 4096              // edges per scatter block (private chunk)
#define THR_S 512               // scatter threads (== RMAXB)
#define THR_B 512               // binprocess threads
#define CAP 9216                // per-bin LDS staging capacity (edges)
#define NBMAX 1024              // max scatter blocks (phase-0 scan handles 2*THR_B)

typedef unsigned int u32;

// ---------------- 64-lane inclusive scan via shfl ----------------------------
__device__ __forceinline__ u32 wave_incl_scan(u32 x) {
    #pragma unroll
    for (int d = 1; d < 64; d <<= 1) {
        u32 y = __shfl_up(x, d);
        if ((int)(threadIdx.x & 63) >= d) x += y;
    }
    return x;
}

// ---------------- LJ force accumulate ----------------------------------------
__device__ __forceinline__ void lj_accum(float4 xd, float4 xs,
                                         float& ax, float& ay, float& az)
{
    float dx = xd.x - xs.x, dy = xd.y - xs.y, dz = xd.z - xs.z;
    float r2 = dx * dx + dy * dy + dz * dz;
    float rr = sqrtf(r2);
    float inv_norm = 1.0f / fmaxf(rr, 1e-12f);
    float rc = fmaxf(rr, MIN_R);
    float s1 = 1.0f / rc;                 // RC = 1
    float s2 = s1 * s1;
    float s6 = s2 * s2 * s2;
    float F = 4.0f * s6 * (12.0f * s6 - 6.0f) * s1;
    float sc = F * inv_norm;
    ax += sc * dx; ay += sc * dy; az += sc * dz;
}

// ---------------- k1: block-private bin-sorted scatter (+ xp pack) -----------
// Block b sorts its SC_BS-edge chunk by bin in LDS, writes it to pk1[b*SC_BS..]
// (coalesced), records tab[b][r] = (boff<<13)|cnt.
__global__ __launch_bounds__(THR_S) void scatter_kernel(
    const float* __restrict__ x, const int* __restrict__ src,
    const int* __restrict__ dst, float4* __restrict__ xp,
    u32* __restrict__ pk1, u32* __restrict__ tab,
    int n_nodes, int n_edges, int NBv, int R)
{
    __shared__ u32 payload[SC_BS];        // 16 KB
    __shared__ u32 hist[RMAXB], loff[RMAXB], lcur[RMAXB];
    __shared__ u32 wsb[8];
    const int b = blockIdx.x, t = threadIdx.x;

    // folded prep: pack x -> xp (grid-stride)
    for (int i = b * THR_S + t; i < n_nodes; i += NBv * THR_S)
        xp[i] = make_float4(x[3 * i + 0], x[3 * i + 1], x[3 * i + 2], 0.0f);

    const int s0 = b * SC_BS;
    const int n  = min(SC_BS, n_edges - s0);
    const int lim = s0 + n;

    hist[t] = 0u;                          // THR_S == RMAXB
    __syncthreads();

    // pass 1: chunk histogram over bins
    for (int e = s0 + t * 4; e < lim; e += THR_S * 4) {
        if (e + 3 < lim) {
            int4 d4 = *(const int4*)(dst + e);
            atomicAdd(&hist[(u32)d4.x >> LOG_NR], 1u);
            atomicAdd(&hist[(u32)d4.y >> LOG_NR], 1u);
            atomicAdd(&hist[(u32)d4.z >> LOG_NR], 1u);
            atomicAdd(&hist[(u32)d4.w >> LOG_NR], 1u);
        } else {
            for (int q = e; q < lim; ++q)
                atomicAdd(&hist[(u32)dst[q] >> LOG_NR], 1u);
        }
    }
    __syncthreads();

    // exclusive scan over 512 bin slots (shfl + wave sums)
    {
        u32 h = hist[t];
        u32 inc = wave_incl_scan(h);
        if ((t & 63) == 63) wsb[t >> 6] = inc;
        __syncthreads();
        u32 pre = 0;
        #pragma unroll
        for (int w = 0; w < 8; ++w) if (w < (t >> 6)) pre += wsb[w];
        u32 ex = pre + inc - h;
        loff[t] = ex; lcur[t] = ex;
    }
    __syncthreads();

    // pass 2: deposit bin-sorted into LDS
    for (int e = s0 + t * 4; e < lim; e += THR_S * 4) {
        if (e + 3 < lim) {
            int4 d4 = *(const int4*)(dst + e);
            int4 s4 = *(const int4*)(src + e);
            #pragma unroll
            for (int q = 0; q < 4; ++q) {
                u32 d = (u32)((q == 0) ? d4.x : (q == 1) ? d4.y : (q == 2) ? d4.z : d4.w);
                u32 sv = (u32)((q == 0) ? s4.x : (q == 1) ? s4.y : (q == 2) ? s4.z : s4.w);
                u32 r = d >> LOG_NR;
                u32 w = ((d & (NR - 1)) << 17) | sv;
                u32 slot = atomicAdd(&lcur[r], 1u);
                payload[slot] = w;
            }
        } else {
            for (int q = e; q < lim; ++q) {
                u32 d = (u32)dst[q];
                u32 sv = (u32)src[q];
                u32 r = d >> LOG_NR;
                u32 w = ((d & (NR - 1)) << 17) | sv;
                u32 slot = atomicAdd(&lcur[r], 1u);
                payload[slot] = w;
            }
        }
    }
    __syncthreads();

    // flush chunk (coalesced, block-private) + table row
    for (int j = t; j < n; j += THR_S) pk1[s0 + j] = payload[j];
    for (int i = t; i < R; i += THR_S)
        tab[(size_t)b * R + i] = (loff[i] << 13) | hist[i];
}

// ---------------- k2: fused bin sort-to-node + register process --------------
// Block r: stage bin r's ragged pk1 segments into LDS, counting-sort by node
// in LDS, then 2-threads-per-node register accumulation, write out directly.
__global__ __launch_bounds__(THR_B, 4) void binprocess_kernel(
    const float4* __restrict__ xp, const u32* __restrict__ pk1,
    const u32* __restrict__ tab, const float* __restrict__ v,
    float* __restrict__ out, int n_nodes, int NBv, int R)
{
    __shared__ u32 buf[CAP];              // 36 KB
    __shared__ u32 sorted[CAP];           // 36 KB
    __shared__ u32 segoff[NBMAX];         // 4 KB
    __shared__ u32 hist[NR], cur[NR], ns[NR];
    __shared__ u32 wsb[8];
    __shared__ u32 shv[2];
    const int r = blockIdx.x, t = threadIdx.x;

    // ---- phase 0: per-segment LDS offsets (scan of counts over NBv) --------
    u32 c0 = 0, c1 = 0;
    if (t < NBv) c0 = tab[(size_t)t * R + r] & 8191u;
    if (t + THR_B < NBv) c1 = tab[(size_t)(t + THR_B) * R + r] & 8191u;
    u32 inc0 = wave_incl_scan(c0);
    if ((t & 63) == 63) wsb[t >> 6] = inc0;
    __syncthreads();
    u32 pre0 = 0;
    #pragma unroll
    for (int w = 0; w < 8; ++w) if (w < (t >> 6)) pre0 += wsb[w];
    u32 s0i = pre0 + inc0;
    if (t == THR_B - 1) shv[0] = s0i;
    __syncthreads();
    const u32 T0 = shv[0];
    u32 inc1 = wave_incl_scan(c1);
    if ((t & 63) == 63) wsb[t >> 6] = inc1;
    __syncthreads();
    u32 pre1 = 0;
    #pragma unroll
    for (int w = 0; w < 8; ++w) if (w < (t >> 6)) pre1 += wsb[w];
    u32 s1i = pre1 + inc1;
    if (t < NBv) segoff[t] = s0i - c0;
    if (t + THR_B < NBv) segoff[t + THR_B] = T0 + s1i - c1;
    if (t == THR_B - 1) shv[1] = T0 + s1i;
    __syncthreads();
    const u32 total = shv[1];

    if (total <= CAP) {
        // ---- phase 1: stage segments into LDS + node histogram -------------
        if (t < NR) hist[t] = 0u;
        __syncthreads();
        for (int j = t; j < NBv; j += THR_B) {
            u32 w = tab[(size_t)j * R + r];
            int cnt = (int)(w & 8191u);
            const u32* seg = pk1 + (size_t)j * SC_BS + (w >> 13);
            u32 base = segoff[j];
            int k = 0;
            for (; k + 3 < cnt; k += 4) {
                u32 w0 = seg[k], w1 = seg[k + 1], w2 = seg[k + 2], w3 = seg[k + 3];
                buf[base + k] = w0; buf[base + k + 1] = w1;
                buf[base + k + 2] = w2; buf[base + k + 3] = w3;
                atomicAdd(&hist[w0 >> 17], 1u);
                atomicAdd(&hist[w1 >> 17], 1u);
                atomicAdd(&hist[w2 >> 17], 1u);
                atomicAdd(&hist[w3 >> 17], 1u);
            }
            for (; k < cnt; ++k) {
                u32 w0 = seg[k];
                buf[base + k] = w0;
                atomicAdd(&hist[w0 >> 17], 1u);
            }
        }
        __syncthreads();

        // ---- phase 2: exclusive scan over 256 node counters ----------------
        {
            u32 h = (t < NR) ? hist[t] : 0u;
            u32 inc = wave_incl_scan(h);
            if ((t & 63) == 63) wsb[t >> 6] = inc;
            __syncthreads();
            u32 pre = 0;
            #pragma unroll
            for (int w = 0; w < 8; ++w) if (w < (t >> 6)) pre += wsb[w];
            if (t < NR) {
                u32 ex = pre + inc - h;
                ns[t] = ex; cur[t] = ex;
            }
        }
        __syncthreads();

        // ---- phase 3: counting-sort into 'sorted' (keep only src id) -------
        for (int i = t; i < (int)total; i += THR_B) {
            u32 w = buf[i];
            u32 p = atomicAdd(&cur[w >> 17], 1u);
            sorted[p] = w & 0x1FFFFu;
        }
        __syncthreads();

        // ---- phase 4: per-node register gather (2 thr/node) + fused out ----
        const int dl = t >> 1, half = t & 1;
        const int node = (r << LOG_NR) + dl;
        if (node < n_nodes) {
            const float4 xd = xp[node];
            const int ee0 = (int)ns[dl];
            const int ee1 = (dl < NR - 1) ? (int)ns[dl + 1] : (int)total;
            float ax = 0.f, ay = 0.f, az = 0.f;
            int e = ee0 + half;
            for (; e + 6 < ee1; e += 8) {
                u32 q0 = sorted[e], q1 = sorted[e + 2];
                u32 q2 = sorted[e + 4], q3 = sorted[e + 6];
                float4 a0 = xp[q0], a1 = xp[q1], a2 = xp[q2], a3 = xp[q3];
                lj_accum(xd, a0, ax, ay, az);
                lj_accum(xd, a1, ax, ay, az);
                lj_accum(xd, a2, ax, ay, az);
                lj_accum(xd, a3, ax, ay, az);
            }
            for (; e < ee1; e += 2) {
                float4 a = xp[sorted[e]];
                lj_accum(xd, a, ax, ay, az);
            }
            ax += __shfl_xor(ax, 1);
            ay += __shfl_xor(ay, 1);
            az += __shfl_xor(az, 1);
            if (half == 0) {
                out[3 * node + 0] = ax - GAMMA * v[3 * node + 0];
                out[3 * node + 1] = ay - GAMMA * v[3 * node + 1];
                out[3 * node + 2] = az - GAMMA * v[3 * node + 2];
            }
        }
    } else {
        // ---- slow correctness path (bin overflow): LDS-atomic accumulate ---
        float* acc = (float*)buf;          // 256*3 floats = 3 KB
        for (int i = t; i < NR * 3; i += THR_B) acc[i] = 0.f;
        __syncthreads();
        for (int j = t; j < NBv; j += THR_B) {
            u32 w = tab[(size_t)j * R + r];
            int cnt = (int)(w & 8191u);
            const u32* seg = pk1 + (size_t)j * SC_BS + (w >> 13);
            for (int k = 0; k < cnt; ++k) {
                u32 w0 = seg[k];
                int u = (int)(w0 >> 17);
                int node = (r << LOG_NR) + u;
                float4 xs = xp[w0 & 0x1FFFFu];
                float4 xd = xp[node];
                float ax = 0.f, ay = 0.f, az = 0.f;
                lj_accum(xd, xs, ax, ay, az);
                unsafeAtomicAdd(&acc[3 * u + 0], ax);
                unsafeAtomicAdd(&acc[3 * u + 1], ay);
                unsafeAtomicAdd(&acc[3 * u + 2], az);
            }
        }
        __syncthreads();
        for (int i = t; i < NR; i += THR_B) {
            int node = (r << LOG_NR) + i;
            if (node < n_nodes) {
                out[3 * node + 0] = acc[3 * i + 0] - GAMMA * v[3 * node + 0];
                out[3 * node + 1] = acc[3 * i + 1] - GAMMA * v[3 * node + 1];
                out[3 * node + 2] = acc[3 * i + 2] - GAMMA * v[3 * node + 2];
            }
        }
    }
}

// ---------------- fallback path ----------------------------------------------
__global__ void init_out_kernel(const float* __restrict__ v,
                                float* __restrict__ out, int n) {
    int i = blockIdx.x * blockDim.x + threadIdx.x;
    if (i < n) out[i] = -GAMMA * v[i];
}

__global__ void edge_atomic_kernel(const float* __restrict__ x,
                                   const int* __restrict__ src,
                                   const int* __restrict__ dst,
                                   float* __restrict__ out, int n_edges) {
    int e = blockIdx.x * blockDim.x + threadIdx.x;
    if (e < n_edges) {
        const int s3 = 3 * src[e], d3 = 3 * dst[e];
        float dx = x[d3 + 0] - x[s3 + 0];
        float dy = x[d3 + 1] - x[s3 + 1];
        float dz = x[d3 + 2] - x[s3 + 2];
        float r2 = dx * dx + dy * dy + dz * dz;
        float rr = sqrtf(r2);
        float inv_norm = 1.0f / fmaxf(rr, 1e-12f);
        float rc = fmaxf(rr, MIN_R);
        float s1 = 1.0f / rc;
        float s2 = s1 * s1;
        float s6 = s2 * s2 * s2;
        float F = 4.0f * s6 * (12.0f * s6 - 6.0f) * s1;
        float sc = F * inv_norm;
        unsafeAtomicAdd(&out[d3 + 0], sc * dx);
        unsafeAtomicAdd(&out[d3 + 1], sc * dy);
        unsafeAtomicAdd(&out[d3 + 2], sc * dz);
    }
}

extern "C" void kernel_launch(void* const* d_in, const int* in_sizes, int n_in,
                              void* d_out, int out_size, void* d_ws, size_t ws_size,
                              hipStream_t stream) {
    const float* x   = (const float*)d_in[0];
    const float* v   = (const float*)d_in[1];
    const int*   src = (const int*)d_in[2];
    const int*   dst = (const int*)d_in[3];
    float* out = (float*)d_out;

    const int n_out   = out_size;
    const int n_nodes = out_size / 3;
    const int n_edges = in_sizes[2];
    const int R   = (n_nodes + NR - 1) / NR;
    const int NBv = (n_edges + SC_BS - 1) / SC_BS;

    // ---- ws layout (bytes) ----
    size_t off = 0;
    auto take = [&off](size_t bytes) {
        size_t o = off;
        off = (off + bytes + 63) & ~(size_t)63;
        return o;
    };
    const size_t xp_o  = take((size_t)n_nodes * 16);
    const size_t tab_o = take((size_t)NBv * R * 4);
    const size_t pk1_o = take((size_t)NBv * SC_BS * 4);
    const size_t need = off;

    const int blk = 256;
    if (n_nodes <= (1 << 17) && R <= RMAXB && NBv <= NBMAX && need <= ws_size) {
        float4* xp = (float4*)((char*)d_ws + xp_o);
        u32* tab   = (u32*)((char*)d_ws + tab_o);
        u32* pk1   = (u32*)((char*)d_ws + pk1_o);

        scatter_kernel<<<NBv, THR_S, 0, stream>>>(x, src, dst, xp, pk1, tab,
                                                  n_nodes, n_edges, NBv, R);
        binprocess_kernel<<<R, THR_B, 0, stream>>>(xp, pk1, tab, v, out,
                                                   n_nodes, NBv, R);
    } else {
        init_out_kernel<<<(n_out + blk - 1) / blk, blk, 0, stream>>>(v, out, n_out);
        edge_atomic_kernel<<<(n_edges + blk - 1) / blk, blk, 0, stream>>>(
            x, src, dst, out, n_edges);
    }
}